// Round 6
// baseline (2115.931 us; speedup 1.0000x reference)
//
#include <hip/hip_runtime.h>
#include <math.h>

// Problem dims
#define BB 32
#define NN 32
#define EE 256
#define HH 1500
#define G4 6000      // 4*HH
#define QIN 512
#define Q1O 600
#define QO 300
#define EV1 1000
#define EV2 100
#define EV3 10
#define PP 496       // N*(N-1)/2
#define ROWS (BB*PP) // 15872
#define BH (BB*HH)   // 48000

// Packed GEMM operand tile: [planes][128 rows][40 shorts]; plane = 5120 shorts
#define TROW 40
#define TPLANE (128 * TROW)   // 5120 shorts per plane

// LSTM fused geometry: 188 blocks x 8 h-indices, K padded to 47*32=1504
#define LKT 47
#define LBLK 188
#define LTILE 2048            // h-buffer shorts per kt: [2 planes][32 rows][32 k]
#define HSZ (LKT * LTILE)     // 96256 shorts per h buffer
#define LTILE_W 1024          // wf shorts per (blk,kt): [32 rows][32 k] single plane
#define HSZW (LKT * LTILE_W)  // 48128 shorts per block slice

typedef __attribute__((ext_vector_type(8))) short bf16x8;
typedef __attribute__((ext_vector_type(4))) float f32x4;

__device__ __forceinline__ float sigm(float x) { return 1.f / (1.f + expf(-x)); }

// RNE round to bf16, kept as fp32 bit pattern (low 16 bits zero)
__device__ __forceinline__ unsigned bf16h(float x) {
    unsigned u = __float_as_uint(x);
    return (u + 0x7FFFu + ((u >> 16) & 1u)) & 0xFFFF0000u;
}

// split float4 -> hi/lo bf16 quads, 8B store each
__device__ __forceinline__ void split4(float4 v, short* hp, short* lp) {
    unsigned h0 = bf16h(v.x), h1 = bf16h(v.y), h2 = bf16h(v.z), h3 = bf16h(v.w);
    float r0 = v.x - __uint_as_float(h0);
    float r1 = v.y - __uint_as_float(h1);
    float r2 = v.z - __uint_as_float(h2);
    float r3 = v.w - __uint_as_float(h3);
    unsigned l0 = bf16h(r0), l1 = bf16h(r1), l2 = bf16h(r2), l3 = bf16h(r3);
    uint2 hw, lw;
    hw.x = (h0 >> 16) | (h1 & 0xFFFF0000u);
    hw.y = (h2 >> 16) | (h3 & 0xFFFF0000u);
    lw.x = (l0 >> 16) | (l1 & 0xFFFF0000u);
    lw.y = (l2 >> 16) | (l3 & 0xFFFF0000u);
    *(uint2*)hp = hw;
    *(uint2*)lp = lw;
}

// hi-plane only version (pure bf16)
__device__ __forceinline__ void hi4(float4 v, short* hp) {
    unsigned h0 = bf16h(v.x), h1 = bf16h(v.y), h2 = bf16h(v.z), h3 = bf16h(v.w);
    uint2 hw;
    hw.x = (h0 >> 16) | (h1 & 0xFFFF0000u);
    hw.y = (h2 >> 16) | (h3 & 0xFFFF0000u);
    *(uint2*)hp = hw;
}

// async 16B global -> LDS (dest wave-uniform; HW adds lane*16B)
#define ASYNC16(dst, src) \
    __builtin_amdgcn_global_load_lds((const __attribute__((address_space(1))) unsigned*)(src), \
                                     (__attribute__((address_space(3))) unsigned*)(dst), 16, 0, 0)

// ---------------- init helpers ----------------
__global__ void k_zero(float* a, int n) {
    int i = blockIdx.x * 256 + threadIdx.x;
    if (i < n) a[i] = 0.f;
}

__global__ void k_iijj(int* iijj) {
    int p = threadIdx.x;
    if (p >= PP) return;
    int i = 0, p0 = 0;
    while (p >= p0 + (NN - 1 - i)) { p0 += NN - 1 - i; i++; }
    iijj[p] = i;
    iijj[PP + p] = i + 1 + (p - p0);
}

// q1 effective bias: q1_b[o] + sum over odd k of q1_w[o][k]  (PE at pos 0)
__global__ void k_q1beff(const float* q1w, const float* q1b, float* beff) {
    int o = blockIdx.x * 256 + threadIdx.x;
    if (o >= Q1O) return;
    float a = q1b[o];
    for (int k = 1; k < QIN; k += 2) a += q1w[o * QIN + k];
    beff[o] = a;
}

__global__ void k_addb(const float* a, const float* b, float* c, int n) {
    int i = blockIdx.x * 256 + threadIdx.x;
    if (i < n) c[i] = a[i] + b[i];
}

// ---------------- transpose (sub-range of columns) ----------------
__global__ void k_transpose(const float* __restrict__ src, float* __restrict__ dst,
                            int R, int C, int c0, int csub) {
    __shared__ float tile[32][33];
    int cb = blockIdx.x * 32, rb = blockIdx.y * 32;
    for (int dy = threadIdx.y; dy < 32; dy += 8) {
        int r = rb + dy, c = cb + threadIdx.x;
        if (r < R && c < csub) tile[dy][threadIdx.x] = src[(size_t)r * C + c0 + c];
    }
    __syncthreads();
    for (int dy = threadIdx.y; dy < 32; dy += 8) {
        int c = cb + dy, r = rb + threadIdx.x;
        if (c < csub && r < R) dst[(size_t)c * R + r] = tile[threadIdx.x][dy];
    }
}

// ---------------- pack fp32 [NR x K from col0] -> blocked bf16 hi/lo tiles ----------------
// dst: [mt][kt][2][128][40] shorts. gridDim.x = KT, gridDim.y = ceil(NR/128). Pads zeroed.
__global__ void k_pack(const float* __restrict__ src, int ld, int col0, int NR, int K,
                       short* __restrict__ D) {
    int kt = blockIdx.x, mt = blockIdx.y, KT = gridDim.x;
    size_t tb = ((size_t)mt * KT + kt) * (2 * TPLANE);
    for (int idx = threadIdx.x; idx < 1024; idx += 256) {
        int rowin = idx >> 3, k4 = (idx & 7) << 2;
        int r = mt * 128 + rowin, k = kt * 32 + k4;
        float4 v = {0.f, 0.f, 0.f, 0.f};
        if (r < NR && k < K) v = *(const float4*)(src + (size_t)r * ld + col0 + k);
        size_t o = tb + rowin * TROW + k4;
        split4(v, D + o, D + o + TPLANE);
    }
}

// ---------------- pack w_hh gate-interleaved, PURE bf16, for fused LSTM ----------------
// wf[blk 188][kt 47][32 rows][32 k] shorts. row = ni*16 + n, n = h_loc*4 + gate,
// h_glob = blk*8 + ni*4 + h_loc. Pads zero.
__global__ void k_pack_wf(const float* __restrict__ whh, short* __restrict__ wf) {
    int kt = blockIdx.x, blk = blockIdx.y;
    size_t tb = ((size_t)blk * LKT + kt) * LTILE_W;
    int t = threadIdx.x;
    int row = t >> 3, k4 = (t & 7) << 2;
    int ni = row >> 4, n = row & 15;
    int g = n & 3, h_glob = blk * 8 + ni * 4 + (n >> 2);
    int k = kt * 32 + k4;
    float4 v = {0.f, 0.f, 0.f, 0.f};
    if (h_glob < HH && k < HH) {
        int j = g * HH + h_glob;
        v = *(const float4*)(whh + (size_t)j * HH + k);
    }
    hi4(v, wf + tb + row * 32 + k4);
}

// ---------------- sort along parts axis: bitonic network (static indices) ----------------
__global__ void k_sort(const float* __restrict__ x, float* __restrict__ seq) {
    int tid = blockIdx.x * 256 + threadIdx.x;
    if (tid >= BB * EE) return;
    int b = tid / EE, e = tid % EE;
    float v[NN];
#pragma unroll
    for (int n = 0; n < NN; n++) v[n] = x[(b * NN + n) * EE + e];
#pragma unroll
    for (int kk = 2; kk <= NN; kk <<= 1) {
#pragma unroll
        for (int jj = kk >> 1; jj > 0; jj >>= 1) {
#pragma unroll
            for (int i = 0; i < NN; i++) {
                int l = i ^ jj;
                if (l > i) {
                    bool up = (i & kk) == 0;
                    float a = v[i], c = v[l];
                    bool sw = up ? (a > c) : (a < c);
                    float lo = sw ? c : a, hi = sw ? a : c;
                    v[i] = lo; v[l] = hi;
                }
            }
        }
    }
#pragma unroll
    for (int n = 0; n < NN; n++) seq[(n * BB + b) * EE + e] = v[n];
}

// ---------------- transpose xg[(n*32+b)][j] -> xgT[n][j][b] ----------------
__global__ void k_xgt(const float* __restrict__ xg, float* __restrict__ xgT) {
    __shared__ float t[32][33];
    int n = blockIdx.z;
    int j0 = blockIdx.x * 32;
    for (int dy = threadIdx.y; dy < 32; dy += 8) {
        int j = j0 + threadIdx.x;
        if (j < G4) t[dy][threadIdx.x] = xg[(size_t)(n * 32 + dy) * G4 + j];
    }
    __syncthreads();
    for (int dy = threadIdx.y; dy < 32; dy += 8) {
        int j = j0 + dy;
        if (j < G4) xgT[(size_t)n * (G4 * BB) + (size_t)j * BB + threadIdx.x] = t[threadIdx.x][dy];
    }
}

// ---------------- pairs gather, writes packed bf16 hi/lo tiles directly ----------------
__global__ void k_pairs(const float* __restrict__ x, const int* __restrict__ iijj,
                        short* __restrict__ P) {
    int idx = blockIdx.x * 256 + threadIdx.x; // quad index
    int r = idx >> 7;
    if (r >= ROWS) return;
    int q = idx & 127, k = q << 2;
    int b = r / PP, p = r - b * PP;
    int part = (k < EE) ? iijj[p] : iijj[PP + p];
    float4 v = *(const float4*)(x + (size_t)(b * NN + part) * EE + (k & (EE - 1)));
    int mt = r >> 7, rowin = r & 127, kt = k >> 5, k4 = k & 31;
    size_t o = ((size_t)mt * 16 + kt) * (2 * TPLANE) + rowin * TROW + k4;
    split4(v, P + o, P + o + TPLANE);
}

// ---------------- templated MFMA GEMM ----------------
// APL: A planes (2 = hi/lo bf16x3, 1 = pure bf16). PPL: pack-out planes.
// B always hi/lo. XCD-grouped 1D grid: grid = 8 * NT * ceil(MT/8).
// Pack-out written unguarded (cols >= N compute exact 0 from zero-padded B).
template<int APL, int PPL>
__global__ __launch_bounds__(256, 2)
void k_gemm_t(const short* __restrict__ Ap, int AKT, const short* __restrict__ Bp,
              const float* __restrict__ bias, const float* __restrict__ pbm,
              float* __restrict__ Cf32, short* __restrict__ P, int PKT,
              int M, int K, int N, int relu) {
    const int ATS = APL * TPLANE;          // A tile shorts
    const int BTS = 2 * TPLANE;            // B tile shorts
    __shared__ __align__(16) short lds[2][APL * TPLANE + 2 * TPLANE];

    int MT = M >> 7, NT = (N + 127) >> 7;
    int bid = blockIdx.x;
    int xcd = bid & 7, rr = bid >> 3;
    int nt = rr % NT, mtc = rr / NT;
    int mt = mtc * 8 + xcd;
    if (mt >= MT) return;

    int tid = threadIdx.x;
    int lane = tid & 63, w = tid >> 6;
    int wr = w >> 1, wc = w & 1;
    int ksteps = (K + 31) >> 5;

    const short* gA = Ap + (size_t)mt * AKT * ATS;
    const short* gB = Bp + (size_t)nt * ksteps * BTS;

#define STAGE(bufi, kt) do { \
        const short* sa_ = gA + (size_t)(kt) * ATS + lane * 8; \
        const short* sb_ = gB + (size_t)(kt) * BTS + lane * 8; \
        for (int c_ = w; c_ < ATS / 512; c_ += 4) \
            ASYNC16(&lds[bufi][c_ * 512], sa_ + c_ * 512); \
        for (int c_ = w; c_ < BTS / 512; c_ += 4) \
            ASYNC16(&lds[bufi][ATS + c_ * 512], sb_ + c_ * 512); \
    } while (0)

    f32x4 acc[4][4];
#pragma unroll
    for (int mi = 0; mi < 4; mi++)
#pragma unroll
        for (int ni = 0; ni < 4; ni++) acc[mi][ni] = (f32x4){0.f, 0.f, 0.f, 0.f};

    int l15 = lane & 15;
    int kc8 = (lane >> 4) << 3;

    STAGE(0, 0);
    __syncthreads();

    int buf = 0;
    for (int kt = 0; kt < ksteps; kt++) {
        if (kt + 1 < ksteps) STAGE(buf ^ 1, kt + 1);

        const short* LA = &lds[buf][0];
        const short* LB = &lds[buf][ATS];

        bf16x8 ah[4], al[4];
#pragma unroll
        for (int mi = 0; mi < 4; mi++) {
            int o = (wr * 64 + mi * 16 + l15) * TROW + kc8;
            ah[mi] = *(const bf16x8*)(LA + o);
            if constexpr (APL == 2) al[mi] = *(const bf16x8*)(LA + TPLANE + o);
        }
#pragma unroll
        for (int ni = 0; ni < 4; ni++) {
            int o = (wc * 64 + ni * 16 + l15) * TROW + kc8;
            bf16x8 bh = *(const bf16x8*)(LB + o);
            bf16x8 bl = *(const bf16x8*)(LB + TPLANE + o);
#pragma unroll
            for (int mi = 0; mi < 4; mi++) {
                acc[mi][ni] = __builtin_amdgcn_mfma_f32_16x16x32_bf16(ah[mi], bh, acc[mi][ni], 0, 0, 0);
                acc[mi][ni] = __builtin_amdgcn_mfma_f32_16x16x32_bf16(ah[mi], bl, acc[mi][ni], 0, 0, 0);
                if constexpr (APL == 2)
                    acc[mi][ni] = __builtin_amdgcn_mfma_f32_16x16x32_bf16(al[mi], bh, acc[mi][ni], 0, 0, 0);
            }
        }
        __syncthreads();
        buf ^= 1;
    }
#undef STAGE

    const int PTS = PPL * TPLANE;
#pragma unroll
    for (int ni = 0; ni < 4; ni++) {
        int col = nt * 128 + wc * 64 + ni * 16 + l15;
        float bb = (bias && col < N) ? bias[col] : 0.f;
#pragma unroll
        for (int mi = 0; mi < 4; mi++) {
            int rbase = mt * 128 + wr * 64 + mi * 16 + ((lane >> 4) << 2);
#pragma unroll
            for (int r4 = 0; r4 < 4; r4++) {
                int row = rbase + r4;
                float v = acc[mi][ni][r4] + bb;
                if (pbm && col < N) v += pbm[(size_t)(row / PP) * N + col];
                if (relu) v = fmaxf(v, 0.f);
                if (Cf32 && col < N) Cf32[(size_t)row * N + col] = v;
                if (P) {
                    unsigned h = bf16h(v);
                    int kt2 = col >> 5, kin = col & 31, rowin = row & 127, mtt = row >> 7;
                    size_t o = ((size_t)mtt * PKT + kt2) * PTS + rowin * TROW + kin;
                    P[o] = (short)(h >> 16);
                    if constexpr (PPL == 2) {
                        unsigned l = bf16h(v - __uint_as_float(h));
                        P[o + TPLANE] = (short)(l >> 16);
                    }
                }
            }
        }
    }
}

// ---------------- persistent fused LSTM: all 32 steps, one launch ----------------
// 188 blocks (<= 256 CUs, 0 LDS -> all co-resident). Device-scope grid barrier
// per step. c-state in registers (owner threads static across steps). h carried
// as bf16 hi/lo planes in hbuf (double-buffered); fp32 ht written at final step.
__global__ __launch_bounds__(256, 1)
void k_lstm_all(const short* __restrict__ wf, short* hbuf,
                const float* __restrict__ xgT, float* ht, unsigned* bar) {
    int tid = threadIdx.x, lane = tid & 63, w4 = tid >> 6;
    int mi = w4 >> 1, ni = w4 & 1;
    int blk = blockIdx.x;
    int l15 = lane & 15, bg = lane >> 4;
    int kc8 = bg << 3;
    int n = l15, g = n & 3;
    int h_glob = blk * 8 + ni * 4 + (n >> 2);
    bool owner = ((n & 3) == 0) && (h_glob < HH);
    int kth = h_glob >> 5, kin = h_glob & 31;

    const short* wp0 = wf + (size_t)blk * HSZW + (ni * 16 + l15) * 32 + kc8;
    int hoff = (mi * 16 + l15) * 32 + kc8;

    f32x4 creg = {0.f, 0.f, 0.f, 0.f};

    for (int step = 0; step < NN; step++) {
        const short* hr = hbuf + (size_t)(step & 1) * HSZ;
        short* hw = hbuf + (size_t)((step + 1) & 1) * HSZ;

        f32x4 accA = {0.f, 0.f, 0.f, 0.f}, accB = {0.f, 0.f, 0.f, 0.f};
        if (h_glob < HH)
            accA = *(const f32x4*)(xgT + (size_t)step * (G4 * BB) +
                                   (size_t)(g * HH + h_glob) * BB + mi * 16 + bg * 4);

        const short* hp0 = hr + hoff;
        // depth-3 software pipeline, named-register rotation
        bf16x8 a0h = *(const bf16x8*)(hp0);
        bf16x8 a0l = *(const bf16x8*)(hp0 + 1024);
        bf16x8 b0  = *(const bf16x8*)(wp0);
        bf16x8 a1h = *(const bf16x8*)(hp0 + LTILE);
        bf16x8 a1l = *(const bf16x8*)(hp0 + LTILE + 1024);
        bf16x8 b1  = *(const bf16x8*)(wp0 + LTILE_W);
        bf16x8 a2h = *(const bf16x8*)(hp0 + 2 * LTILE);
        bf16x8 a2l = *(const bf16x8*)(hp0 + 2 * LTILE + 1024);
        bf16x8 b2  = *(const bf16x8*)(wp0 + 2 * LTILE_W);
        for (int kt = 0; kt < LKT; kt++) {
            bf16x8 a3h, a3l, b3;
            if (kt + 3 < LKT) {
                const short* hp = hp0 + (size_t)(kt + 3) * LTILE;
                const short* wp = wp0 + (size_t)(kt + 3) * LTILE_W;
                a3h = *(const bf16x8*)(hp);
                a3l = *(const bf16x8*)(hp + 1024);
                b3  = *(const bf16x8*)(wp);
            }
            accA = __builtin_amdgcn_mfma_f32_16x16x32_bf16(a0h, b0, accA, 0, 0, 0);
            accB = __builtin_amdgcn_mfma_f32_16x16x32_bf16(a0l, b0, accB, 0, 0, 0);
            a0h = a1h; a0l = a1l; b0 = b1;
            a1h = a2h; a1l = a2l; b1 = b2;
            a2h = a3h; a2l = a3l; b2 = b3;
        }
        f32x4 acc = accA + accB;

        float gg[4][4];
#pragma unroll
        for (int r = 0; r < 4; r++) {
            float a = acc[r];
            gg[0][r] = a;
            gg[1][r] = __shfl_xor(a, 1);
            gg[2][r] = __shfl_xor(a, 2);
            gg[3][r] = __shfl_xor(a, 3);
        }

        if (owner) {
#pragma unroll
            for (int r = 0; r < 4; r++) {
                int b = mi * 16 + bg * 4 + r;
                float cn = sigm(gg[1][r]) * creg[r] + sigm(gg[0][r]) * tanhf(gg[2][r]);
                creg[r] = cn;
                float hv = sigm(gg[3][r]) * tanhf(cn);
                if (step == NN - 1) {
                    ht[h_glob * BB + b] = hv;
                } else {
                    unsigned hh = bf16h(hv);
                    unsigned hl = bf16h(hv - __uint_as_float(hh));
                    size_t o = (size_t)kth * LTILE + b * 32 + kin;
                    hw[o] = (short)(hh >> 16);
                    hw[o + 1024] = (short)(hl >> 16);
                }
            }
        }

        if (step < NN - 1) {
            __threadfence();           // release this block's hw writes (agent scope)
            __syncthreads();
            if (tid == 0) {
                unsigned gcur = __hip_atomic_load(bar + 1, __ATOMIC_RELAXED,
                                                  __HIP_MEMORY_SCOPE_AGENT);
                unsigned a = __hip_atomic_fetch_add(bar, 1u, __ATOMIC_ACQ_REL,
                                                    __HIP_MEMORY_SCOPE_AGENT) + 1u;
                if (a == (unsigned)LBLK) {
                    __hip_atomic_store(bar, 0u, __ATOMIC_RELAXED, __HIP_MEMORY_SCOPE_AGENT);
                    __hip_atomic_store(bar + 1, gcur + 1u, __ATOMIC_RELEASE,
                                       __HIP_MEMORY_SCOPE_AGENT);
                } else {
                    while (__hip_atomic_load(bar + 1, __ATOMIC_ACQUIRE,
                                             __HIP_MEMORY_SCOPE_AGENT) == gcur) {}
                }
            }
            __syncthreads();
            __threadfence();           // acquire: invalidate caches before reading hr
        }
    }
}

// ---------------- plan-side e1 bias (plan in ht layout [h][b]) ----------------
__global__ void k_pb(const float* __restrict__ ht, const float* __restrict__ e1at,
                     const float* __restrict__ e1b, float* __restrict__ pb) {
    __shared__ float ps[HH];
    int b = blockIdx.y;
    for (int idx = threadIdx.x; idx < HH; idx += 256) ps[idx] = ht[(size_t)idx * BB + b];
    __syncthreads();
    int o = blockIdx.x * 256 + threadIdx.x;
    if (o >= EV1) return;
    float acc = e1b[o];
    for (int k = 0; k < HH; k++) acc += ps[k] * e1at[(size_t)k * EV1 + o];
    pb[b * EV1 + o] = acc;
}

// ---------------- fused e3 + e4 tail ----------------
__global__ void k_e34(const float* __restrict__ e2out, const float* __restrict__ e3t,
                      const float* __restrict__ e3b, const float* __restrict__ e4w,
                      const float* __restrict__ e4b, float* __restrict__ out) {
    __shared__ float wt[EV2 * EV3];
    for (int idx = threadIdx.x; idx < EV2 * EV3; idx += 256) wt[idx] = e3t[idx];
    __syncthreads();
    int r = blockIdx.x * 256 + threadIdx.x;
    if (r >= ROWS) return;
    float h3[EV3];
#pragma unroll
    for (int o3 = 0; o3 < EV3; o3++) h3[o3] = e3b[o3];
    for (int k = 0; k < EV2; k++) {
        float v = e2out[(size_t)r * EV2 + k];
#pragma unroll
        for (int o3 = 0; o3 < EV3; o3++) h3[o3] += v * wt[k * EV3 + o3];
    }
    float acc = e4b[0];
#pragma unroll
    for (int o3 = 0; o3 < EV3; o3++) acc += fmaxf(h3[o3], 0.f) * e4w[o3];
    out[r] = fmaxf(acc, 0.f);
}

// ---------------- host launch ----------------
extern "C" void kernel_launch(void* const* d_in, const int* in_sizes, int n_in,
                              void* d_out, int out_size, void* d_ws, size_t ws_size,
                              hipStream_t stream) {
    const float* x    = (const float*)d_in[0];
    const float* w_ih = (const float*)d_in[1];
    const float* w_hh = (const float*)d_in[2];
    const float* b_ih = (const float*)d_in[3];
    const float* b_hh = (const float*)d_in[4];
    const float* q1_w = (const float*)d_in[5];
    const float* q1_b = (const float*)d_in[6];
    const float* q2_w = (const float*)d_in[7];
    const float* q2_b = (const float*)d_in[8];
    const float* e1_w = (const float*)d_in[9];
    const float* e1_b = (const float*)d_in[10];
    const float* e2_w = (const float*)d_in[11];
    const float* e2_b = (const float*)d_in[12];
    const float* e3_w = (const float*)d_in[13];
    const float* e3_b = (const float*)d_in[14];
    const float* e4_w = (const float*)d_in[15];
    const float* e4_b = (const float*)d_in[16];
    float* out = (float*)d_out;
    float* ws = (float*)d_ws;

    // ---- workspace layout (float offsets) ----
    // regionA (23M floats), phase-aliased:
    //  pack/xg : wf [0,4.53M) | xg [4.6M,10.75M) | seq_p [10.8M,11.13M) | wih_p [11.2M,13.13M)
    //  LSTM    : wf [0,4.53M)   (xg dead after xgT)
    //  q1      : pairs_p [0,10.16M) | q1out_p [10.2M,22.9M)   (wf dead)
    //  e1      : e1out_p [0,10.16M)  (pairs_p dead; q1out_p dead after q2)
    //  e2      : e1out_p | e2out [20.4M,21.99M)
    size_t off = 0;
    float* seq    = ws + off; off += (size_t)NN * BB * EE;   // 262,144
    size_t regionA = off; off += 23000000;
    short* wf       = (short*)(ws + regionA);                // 9,048,064 sh
    float* xg       = ws + regionA + 4600000;                // 6,144,000 fl
    short* seq_p    = (short*)(ws + regionA + 10800000);     // 655,360 sh
    short* wih_p    = (short*)(ws + regionA + 11200000);     // 3,850,240 sh
    short* pairs_p  = (short*)(ws + regionA);                // 20,316,160 sh
    short* q1out_p  = (short*)(ws + regionA + 10200000);     // 25,395,200 sh (hi/lo)
    short* e1out_p  = (short*)(ws + regionA);                // 124*32*5120 = 20,316,160 sh (bf16)
    float* e2out    = ws + regionA + 20400000;               // 1,587,200 fl
    float* xgT    = ws + off; off += 7618560;                // 6,144,000 fl; q2out_p alias
    short* q2out_p  = (short*)xgT;                           // 124*12*5120 = 7,618,560 sh (bf16)
    float* ht     = ws + off; off += BH;
    short* hbuf   = (short*)(ws + off); off += 96256;        // 2 x HSZ shorts
    short* q1w_p  = (short*)(ws + off); off += 409600;
    short* q2w_p  = (short*)(ws + off); off += 291840;
    short* e1w_p  = (short*)(ws + off); off += 409600;
    short* e2w_p  = (short*)(ws + off); off += 163840;
    float* e1at   = ws + off; off += (size_t)HH * EV1;
    float* e3t    = ws + off; off += 1024;
    float* pb     = ws + off; off += BB * EV1;
    float* q1beff = ws + off; off += 1024;
    float* bsum   = ws + off; off += 6016;
    int*   iijj   = (int*)(ws + off); off += 1024;
    unsigned* bar = (unsigned*)(ws + off); off += 256;

    dim3 tb(32, 8);

    // init (bar + hbuf re-zeroed every launch: workspace may be re-poisoned)
    k_iijj<<<1, 512, 0, stream>>>(iijj);
    k_q1beff<<<3, 256, 0, stream>>>(q1_w, q1_b, q1beff);
    k_addb<<<24, 256, 0, stream>>>(b_ih, b_hh, bsum, G4);
    k_zero<<<376, 256, 0, stream>>>((float*)hbuf, 96256);
    k_zero<<<1, 256, 0, stream>>>((float*)bar, 256);

    // weight transforms
    k_pack_wf<<<dim3(LKT, LBLK), 256, 0, stream>>>(w_hh, wf);
    k_transpose<<<dim3(47, 32), tb, 0, stream>>>(e1_w, e1at, EV1, HH + QO, 0, HH);
    k_transpose<<<dim3(4, 1), tb, 0, stream>>>(e3_w, e3t, EV3, EV2, 0, EV2);
    k_pack<<<dim3(8, 47), 256, 0, stream>>>(w_ih, EE, 0, G4, EE, wih_p);
    k_pack<<<dim3(16, 5), 256, 0, stream>>>(q1_w, QIN, 0, Q1O, QIN, q1w_p);
    k_pack<<<dim3(19, 3), 256, 0, stream>>>(q2_w, Q1O, 0, QO, Q1O, q2w_p);
    k_pack<<<dim3(10, 8), 256, 0, stream>>>(e1_w, HH + QO, HH, EV1, QO, e1w_p);
    k_pack<<<dim3(32, 1), 256, 0, stream>>>(e2_w, EV1, 0, EV2, EV1, e2w_p);

    // sort + pack seq + x-side gates (xg = seq @ w_ih^T + bsum), transpose to [n][j][b]
    k_sort<<<32, 256, 0, stream>>>(x, seq);
    k_pack<<<dim3(8, 8), 256, 0, stream>>>(seq, EE, 0, 1024, EE, seq_p);
    k_gemm_t<2, 2><<<8 * 47 * 1, 256, 0, stream>>>(seq_p, 8, wih_p, bsum, nullptr,
                                                   xg, nullptr, 0, 1024, EE, G4, 0);
    k_xgt<<<dim3(188, 1, 32), tb, 0, stream>>>(xg, xgT);

    // LSTM: single persistent kernel, 32 steps with internal grid barrier
    k_lstm_all<<<LBLK, 256, 0, stream>>>(wf, hbuf, xgT, ht, bar);

    // evaluator plan-side bias (includes e1_b)
    k_pb<<<dim3(4, BB), 256, 0, stream>>>(ht, e1at, e1_b, pb);

    // pair MLP (packed pipeline; pairs_p overwrites dead wf — after LSTM)
    k_pairs<<<7936, 256, 0, stream>>>(x, iijj, pairs_p);
    k_gemm_t<2, 2><<<8 * 5 * 16, 256, 0, stream>>>(pairs_p, 16, q1w_p, q1beff, nullptr,
                                                   nullptr, q1out_p, 20, ROWS, QIN, Q1O, 1);
    k_gemm_t<2, 1><<<8 * 3 * 16, 256, 0, stream>>>(q1out_p, 20, q2w_p, q2_b, nullptr,
                                                   nullptr, q2out_p, 12, ROWS, Q1O, QO, 1);
    k_gemm_t<1, 1><<<8 * 8 * 16, 256, 0, stream>>>(q2out_p, 12, e1w_p, nullptr, pb,
                                                   nullptr, e1out_p, 32, ROWS, QO, EV1, 1);
    k_gemm_t<1, 1><<<8 * 1 * 16, 256, 0, stream>>>(e1out_p, 32, e2w_p, e2_b, nullptr,
                                                   e2out, nullptr, 0, ROWS, EV1, EV2, 1);
    k_e34<<<62, 256, 0, stream>>>(e2out, e3t, e3_b, e4_w, e4_b, out);
}

// Round 7
// 887.682 us; speedup vs baseline: 2.3837x; 2.3837x over previous
//
#include <hip/hip_runtime.h>
#include <math.h>

// Problem dims
#define BB 32
#define NN 32
#define EE 256
#define HH 1500
#define G4 6000      // 4*HH
#define QIN 512
#define Q1O 600
#define QO 300
#define EV1 1000
#define EV2 100
#define EV3 10
#define PP 496       // N*(N-1)/2
#define ROWS (BB*PP) // 15872
#define BH (BB*HH)   // 48000

// Packed GEMM operand tile: [planes][128 rows][40 shorts]; plane = 5120 shorts
#define TROW 40
#define TPLANE (128 * TROW)   // 5120 shorts per plane

// LSTM fused geometry: 188 blocks x 8 h-indices, K padded to 47*32=1504
#define LKT 47
#define LBLK 188
#define LTILE 2048            // h-buffer shorts per kt: [2 planes][32 rows][32 k]
#define HSZ (LKT * LTILE)     // 96256 shorts per h buffer
#define LTILE_W 1024          // wf shorts per (blk,kt): [32 rows][32 k] single plane
#define HSZW (LKT * LTILE_W)  // 48128 shorts per block slice

typedef __attribute__((ext_vector_type(8))) short bf16x8;
typedef __attribute__((ext_vector_type(4))) float f32x4;

__device__ __forceinline__ float sigm(float x) { return 1.f / (1.f + expf(-x)); }

// RNE round to bf16, kept as fp32 bit pattern (low 16 bits zero)
__device__ __forceinline__ unsigned bf16h(float x) {
    unsigned u = __float_as_uint(x);
    return (u + 0x7FFFu + ((u >> 16) & 1u)) & 0xFFFF0000u;
}

// split float4 -> hi/lo bf16 quads, 8B store each
__device__ __forceinline__ void split4(float4 v, short* hp, short* lp) {
    unsigned h0 = bf16h(v.x), h1 = bf16h(v.y), h2 = bf16h(v.z), h3 = bf16h(v.w);
    float r0 = v.x - __uint_as_float(h0);
    float r1 = v.y - __uint_as_float(h1);
    float r2 = v.z - __uint_as_float(h2);
    float r3 = v.w - __uint_as_float(h3);
    unsigned l0 = bf16h(r0), l1 = bf16h(r1), l2 = bf16h(r2), l3 = bf16h(r3);
    uint2 hw, lw;
    hw.x = (h0 >> 16) | (h1 & 0xFFFF0000u);
    hw.y = (h2 >> 16) | (h3 & 0xFFFF0000u);
    lw.x = (l0 >> 16) | (l1 & 0xFFFF0000u);
    lw.y = (l2 >> 16) | (l3 & 0xFFFF0000u);
    *(uint2*)hp = hw;
    *(uint2*)lp = lw;
}

// hi-plane only version (pure bf16)
__device__ __forceinline__ void hi4(float4 v, short* hp) {
    unsigned h0 = bf16h(v.x), h1 = bf16h(v.y), h2 = bf16h(v.z), h3 = bf16h(v.w);
    uint2 hw;
    hw.x = (h0 >> 16) | (h1 & 0xFFFF0000u);
    hw.y = (h2 >> 16) | (h3 & 0xFFFF0000u);
    *(uint2*)hp = hw;
}

// async 16B global -> LDS (dest wave-uniform; HW adds lane*16B)
#define ASYNC16(dst, src) \
    __builtin_amdgcn_global_load_lds((const __attribute__((address_space(1))) unsigned*)(src), \
                                     (__attribute__((address_space(3))) unsigned*)(dst), 16, 0, 0)

// ---------------- init helpers ----------------
__global__ void k_zero(float* a, int n) {
    int i = blockIdx.x * 256 + threadIdx.x;
    if (i < n) a[i] = 0.f;
}

__global__ void k_iijj(int* iijj) {
    int p = threadIdx.x;
    if (p >= PP) return;
    int i = 0, p0 = 0;
    while (p >= p0 + (NN - 1 - i)) { p0 += NN - 1 - i; i++; }
    iijj[p] = i;
    iijj[PP + p] = i + 1 + (p - p0);
}

// q1 effective bias: q1_b[o] + sum over odd k of q1_w[o][k]  (PE at pos 0)
__global__ void k_q1beff(const float* q1w, const float* q1b, float* beff) {
    int o = blockIdx.x * 256 + threadIdx.x;
    if (o >= Q1O) return;
    float a = q1b[o];
    for (int k = 1; k < QIN; k += 2) a += q1w[o * QIN + k];
    beff[o] = a;
}

__global__ void k_addb(const float* a, const float* b, float* c, int n) {
    int i = blockIdx.x * 256 + threadIdx.x;
    if (i < n) c[i] = a[i] + b[i];
}

// ---------------- transpose (sub-range of columns) ----------------
__global__ void k_transpose(const float* __restrict__ src, float* __restrict__ dst,
                            int R, int C, int c0, int csub) {
    __shared__ float tile[32][33];
    int cb = blockIdx.x * 32, rb = blockIdx.y * 32;
    for (int dy = threadIdx.y; dy < 32; dy += 8) {
        int r = rb + dy, c = cb + threadIdx.x;
        if (r < R && c < csub) tile[dy][threadIdx.x] = src[(size_t)r * C + c0 + c];
    }
    __syncthreads();
    for (int dy = threadIdx.y; dy < 32; dy += 8) {
        int c = cb + dy, r = rb + threadIdx.x;
        if (c < csub && r < R) dst[(size_t)c * R + r] = tile[threadIdx.x][dy];
    }
}

// ---------------- pack fp32 [NR x K from col0] -> blocked bf16 hi/lo tiles ----------------
// dst: [mt][kt][2][128][40] shorts. gridDim.x = KT, gridDim.y = ceil(NR/128). Pads zeroed.
__global__ void k_pack(const float* __restrict__ src, int ld, int col0, int NR, int K,
                       short* __restrict__ D) {
    int kt = blockIdx.x, mt = blockIdx.y, KT = gridDim.x;
    size_t tb = ((size_t)mt * KT + kt) * (2 * TPLANE);
    for (int idx = threadIdx.x; idx < 1024; idx += 256) {
        int rowin = idx >> 3, k4 = (idx & 7) << 2;
        int r = mt * 128 + rowin, k = kt * 32 + k4;
        float4 v = {0.f, 0.f, 0.f, 0.f};
        if (r < NR && k < K) v = *(const float4*)(src + (size_t)r * ld + col0 + k);
        size_t o = tb + rowin * TROW + k4;
        split4(v, D + o, D + o + TPLANE);
    }
}

// ---------------- pack w_hh gate-interleaved, PURE bf16, for fused LSTM ----------------
// wf[blk 188][kt 47][32 rows][32 k] shorts. row = ni*16 + n, n = h_loc*4 + gate,
// h_glob = blk*8 + ni*4 + h_loc. Pads zero.
__global__ void k_pack_wf(const float* __restrict__ whh, short* __restrict__ wf) {
    int kt = blockIdx.x, blk = blockIdx.y;
    size_t tb = ((size_t)blk * LKT + kt) * LTILE_W;
    int t = threadIdx.x;
    int row = t >> 3, k4 = (t & 7) << 2;
    int ni = row >> 4, n = row & 15;
    int g = n & 3, h_glob = blk * 8 + ni * 4 + (n >> 2);
    int k = kt * 32 + k4;
    float4 v = {0.f, 0.f, 0.f, 0.f};
    if (h_glob < HH && k < HH) {
        int j = g * HH + h_glob;
        v = *(const float4*)(whh + (size_t)j * HH + k);
    }
    hi4(v, wf + tb + row * 32 + k4);
}

// ---------------- sort along parts axis: bitonic network (static indices) ----------------
__global__ void k_sort(const float* __restrict__ x, float* __restrict__ seq) {
    int tid = blockIdx.x * 256 + threadIdx.x;
    if (tid >= BB * EE) return;
    int b = tid / EE, e = tid % EE;
    float v[NN];
#pragma unroll
    for (int n = 0; n < NN; n++) v[n] = x[(b * NN + n) * EE + e];
#pragma unroll
    for (int kk = 2; kk <= NN; kk <<= 1) {
#pragma unroll
        for (int jj = kk >> 1; jj > 0; jj >>= 1) {
#pragma unroll
            for (int i = 0; i < NN; i++) {
                int l = i ^ jj;
                if (l > i) {
                    bool up = (i & kk) == 0;
                    float a = v[i], c = v[l];
                    bool sw = up ? (a > c) : (a < c);
                    float lo = sw ? c : a, hi = sw ? a : c;
                    v[i] = lo; v[l] = hi;
                }
            }
        }
    }
#pragma unroll
    for (int n = 0; n < NN; n++) seq[(n * BB + b) * EE + e] = v[n];
}

// ---------------- transpose xg[(n*32+b)][j] -> xgT[n][j][b] ----------------
__global__ void k_xgt(const float* __restrict__ xg, float* __restrict__ xgT) {
    __shared__ float t[32][33];
    int n = blockIdx.z;
    int j0 = blockIdx.x * 32;
    for (int dy = threadIdx.y; dy < 32; dy += 8) {
        int j = j0 + threadIdx.x;
        if (j < G4) t[dy][threadIdx.x] = xg[(size_t)(n * 32 + dy) * G4 + j];
    }
    __syncthreads();
    for (int dy = threadIdx.y; dy < 32; dy += 8) {
        int j = j0 + dy;
        if (j < G4) xgT[(size_t)n * (G4 * BB) + (size_t)j * BB + threadIdx.x] = t[threadIdx.x][dy];
    }
}

// ---------------- pairs gather, writes packed bf16 hi/lo tiles directly ----------------
__global__ void k_pairs(const float* __restrict__ x, const int* __restrict__ iijj,
                        short* __restrict__ P) {
    int idx = blockIdx.x * 256 + threadIdx.x; // quad index
    int r = idx >> 7;
    if (r >= ROWS) return;
    int q = idx & 127, k = q << 2;
    int b = r / PP, p = r - b * PP;
    int part = (k < EE) ? iijj[p] : iijj[PP + p];
    float4 v = *(const float4*)(x + (size_t)(b * NN + part) * EE + (k & (EE - 1)));
    int mt = r >> 7, rowin = r & 127, kt = k >> 5, k4 = k & 31;
    size_t o = ((size_t)mt * 16 + kt) * (2 * TPLANE) + rowin * TROW + k4;
    split4(v, P + o, P + o + TPLANE);
}

// ---------------- templated MFMA GEMM ----------------
// APL: A planes (2 = hi/lo bf16x3, 1 = pure bf16). PPL: pack-out planes.
// B always hi/lo. XCD-grouped 1D grid: grid = 8 * NT * ceil(MT/8).
// Pack-out written unguarded (cols >= N compute exact 0 from zero-padded B).
template<int APL, int PPL>
__global__ __launch_bounds__(256, 2)
void k_gemm_t(const short* __restrict__ Ap, int AKT, const short* __restrict__ Bp,
              const float* __restrict__ bias, const float* __restrict__ pbm,
              float* __restrict__ Cf32, short* __restrict__ P, int PKT,
              int M, int K, int N, int relu) {
    const int ATS = APL * TPLANE;          // A tile shorts
    const int BTS = 2 * TPLANE;            // B tile shorts
    __shared__ __align__(16) short lds[2][APL * TPLANE + 2 * TPLANE];

    int MT = M >> 7, NT = (N + 127) >> 7;
    int bid = blockIdx.x;
    int xcd = bid & 7, rr = bid >> 3;
    int nt = rr % NT, mtc = rr / NT;
    int mt = mtc * 8 + xcd;
    if (mt >= MT) return;

    int tid = threadIdx.x;
    int lane = tid & 63, w = tid >> 6;
    int wr = w >> 1, wc = w & 1;
    int ksteps = (K + 31) >> 5;

    const short* gA = Ap + (size_t)mt * AKT * ATS;
    const short* gB = Bp + (size_t)nt * ksteps * BTS;

#define STAGE(bufi, kt) do { \
        const short* sa_ = gA + (size_t)(kt) * ATS + lane * 8; \
        const short* sb_ = gB + (size_t)(kt) * BTS + lane * 8; \
        for (int c_ = w; c_ < ATS / 512; c_ += 4) \
            ASYNC16(&lds[bufi][c_ * 512], sa_ + c_ * 512); \
        for (int c_ = w; c_ < BTS / 512; c_ += 4) \
            ASYNC16(&lds[bufi][ATS + c_ * 512], sb_ + c_ * 512); \
    } while (0)

    f32x4 acc[4][4];
#pragma unroll
    for (int mi = 0; mi < 4; mi++)
#pragma unroll
        for (int ni = 0; ni < 4; ni++) acc[mi][ni] = (f32x4){0.f, 0.f, 0.f, 0.f};

    int l15 = lane & 15;
    int kc8 = (lane >> 4) << 3;

    STAGE(0, 0);
    __syncthreads();

    int buf = 0;
    for (int kt = 0; kt < ksteps; kt++) {
        if (kt + 1 < ksteps) STAGE(buf ^ 1, kt + 1);

        const short* LA = &lds[buf][0];
        const short* LB = &lds[buf][ATS];

        bf16x8 ah[4], al[4];
#pragma unroll
        for (int mi = 0; mi < 4; mi++) {
            int o = (wr * 64 + mi * 16 + l15) * TROW + kc8;
            ah[mi] = *(const bf16x8*)(LA + o);
            if constexpr (APL == 2) al[mi] = *(const bf16x8*)(LA + TPLANE + o);
        }
#pragma unroll
        for (int ni = 0; ni < 4; ni++) {
            int o = (wc * 64 + ni * 16 + l15) * TROW + kc8;
            bf16x8 bh = *(const bf16x8*)(LB + o);
            bf16x8 bl = *(const bf16x8*)(LB + TPLANE + o);
#pragma unroll
            for (int mi = 0; mi < 4; mi++) {
                acc[mi][ni] = __builtin_amdgcn_mfma_f32_16x16x32_bf16(ah[mi], bh, acc[mi][ni], 0, 0, 0);
                acc[mi][ni] = __builtin_amdgcn_mfma_f32_16x16x32_bf16(ah[mi], bl, acc[mi][ni], 0, 0, 0);
                if constexpr (APL == 2)
                    acc[mi][ni] = __builtin_amdgcn_mfma_f32_16x16x32_bf16(al[mi], bh, acc[mi][ni], 0, 0, 0);
            }
        }
        __syncthreads();
        buf ^= 1;
    }
#undef STAGE

    const int PTS = PPL * TPLANE;
#pragma unroll
    for (int ni = 0; ni < 4; ni++) {
        int col = nt * 128 + wc * 64 + ni * 16 + l15;
        float bb = (bias && col < N) ? bias[col] : 0.f;
#pragma unroll
        for (int mi = 0; mi < 4; mi++) {
            int rbase = mt * 128 + wr * 64 + mi * 16 + ((lane >> 4) << 2);
#pragma unroll
            for (int r4 = 0; r4 < 4; r4++) {
                int row = rbase + r4;
                float v = acc[mi][ni][r4] + bb;
                if (pbm && col < N) v += pbm[(size_t)(row / PP) * N + col];
                if (relu) v = fmaxf(v, 0.f);
                if (Cf32 && col < N) Cf32[(size_t)row * N + col] = v;
                if (P) {
                    unsigned h = bf16h(v);
                    int kt2 = col >> 5, kin = col & 31, rowin = row & 127, mtt = row >> 7;
                    size_t o = ((size_t)mtt * PKT + kt2) * PTS + rowin * TROW + kin;
                    P[o] = (short)(h >> 16);
                    if constexpr (PPL == 2) {
                        unsigned l = bf16h(v - __uint_as_float(h));
                        P[o + TPLANE] = (short)(l >> 16);
                    }
                }
            }
        }
    }
}

// ---------------- fused LSTM step: 8 waves, k-split 2-way + LDS reduce ----------------
// 188 blocks x 512 thr. wave = (ks, mi, ni); ks halves the kt range (dependent-chain
// 47 -> 24), LDS-reduce ks=1 partials into ks=0. Block owns h [blk*8, blk*8+8).
// acc init = xgT (x-side preactivation). h in hi/lo bf16 planes; weights PURE bf16
// (L2-resident across steps). 4-lane shuffle gathers gates; owner lanes update state.
__global__ __launch_bounds__(512, 1)
void k_lstm_step(const short* __restrict__ wf, const short* __restrict__ hbuf_r,
                 short* __restrict__ hbuf_w, const float* __restrict__ xgT_n,
                 float* __restrict__ ct, float* __restrict__ ht) {
    __shared__ f32x4 red[4][64];
    int tid = threadIdx.x, lane = tid & 63, wave = tid >> 6;
    int ks = wave >> 2, w4 = wave & 3;
    int mi = w4 >> 1, ni = w4 & 1;
    int blk = blockIdx.x;
    int l15 = lane & 15, bg = lane >> 4;
    int kc8 = bg << 3;
    int n = l15, g = n & 3;
    int h_glob = blk * 8 + ni * 4 + (n >> 2);
    int kt0 = ks * 24, ktend = ks ? LKT : 24;

    f32x4 accA = {0.f, 0.f, 0.f, 0.f}, accB = {0.f, 0.f, 0.f, 0.f};
    if (ks == 0 && h_glob < HH)
        accA = *(const f32x4*)(xgT_n + (size_t)(g * HH + h_glob) * BB + mi * 16 + bg * 4);

    const short* wp0 = wf + (size_t)blk * HSZW + (ni * 16 + l15) * 32 + kc8;
    const short* hp0 = hbuf_r + (mi * 16 + l15) * 32 + kc8;

    // depth-3 software pipeline, named-register rotation
    bf16x8 a0h = *(const bf16x8*)(hp0 + (size_t)kt0 * LTILE);
    bf16x8 a0l = *(const bf16x8*)(hp0 + (size_t)kt0 * LTILE + 1024);
    bf16x8 b0  = *(const bf16x8*)(wp0 + (size_t)kt0 * LTILE_W);
    bf16x8 a1h = *(const bf16x8*)(hp0 + (size_t)(kt0 + 1) * LTILE);
    bf16x8 a1l = *(const bf16x8*)(hp0 + (size_t)(kt0 + 1) * LTILE + 1024);
    bf16x8 b1  = *(const bf16x8*)(wp0 + (size_t)(kt0 + 1) * LTILE_W);
    bf16x8 a2h = *(const bf16x8*)(hp0 + (size_t)(kt0 + 2) * LTILE);
    bf16x8 a2l = *(const bf16x8*)(hp0 + (size_t)(kt0 + 2) * LTILE + 1024);
    bf16x8 b2  = *(const bf16x8*)(wp0 + (size_t)(kt0 + 2) * LTILE_W);
    for (int kt = kt0; kt < ktend; kt++) {
        bf16x8 a3h, a3l, b3;
        if (kt + 3 < ktend) {
            const short* hp = hp0 + (size_t)(kt + 3) * LTILE;
            const short* wp = wp0 + (size_t)(kt + 3) * LTILE_W;
            a3h = *(const bf16x8*)(hp);
            a3l = *(const bf16x8*)(hp + 1024);
            b3  = *(const bf16x8*)(wp);
        }
        accA = __builtin_amdgcn_mfma_f32_16x16x32_bf16(a0h, b0, accA, 0, 0, 0);
        accB = __builtin_amdgcn_mfma_f32_16x16x32_bf16(a0l, b0, accB, 0, 0, 0);
        a0h = a1h; a0l = a1l; b0 = b1;
        a1h = a2h; a1l = a2l; b1 = b2;
        a2h = a3h; a2l = a3l; b2 = b3;
    }
    f32x4 acc = accA + accB;

    // reduce ks=1 partials into ks=0 waves
    if (ks == 1) red[w4][lane] = acc;
    __syncthreads();
    if (ks == 1) return;
    acc += red[w4][lane];

    // gather the 4 gates across the 4-lane group (lane n, n^1, n^2, n^3)
    float gg[4][4];
#pragma unroll
    for (int r = 0; r < 4; r++) {
        float a = acc[r];
        gg[0][r] = a;
        gg[1][r] = __shfl_xor(a, 1);
        gg[2][r] = __shfl_xor(a, 2);
        gg[3][r] = __shfl_xor(a, 3);
    }

    if ((n & 3) == 0 && h_glob < HH) {
        int kth = h_glob >> 5, kin = h_glob & 31;
#pragma unroll
        for (int r = 0; r < 4; r++) {
            int b = mi * 16 + bg * 4 + r;
            float ci = ct[h_glob * BB + b];
            float cn = sigm(gg[1][r]) * ci + sigm(gg[0][r]) * tanhf(gg[2][r]);
            ct[h_glob * BB + b] = cn;
            float hv = sigm(gg[3][r]) * tanhf(cn);
            ht[h_glob * BB + b] = hv;
            unsigned hh = bf16h(hv);
            unsigned hl = bf16h(hv - __uint_as_float(hh));
            size_t o = (size_t)kth * LTILE + b * 32 + kin;
            hbuf_w[o] = (short)(hh >> 16);
            hbuf_w[o + 1024] = (short)(hl >> 16);
        }
    }
}

// ---------------- plan-side e1 bias (plan in ht layout [h][b]) ----------------
__global__ void k_pb(const float* __restrict__ ht, const float* __restrict__ e1at,
                     const float* __restrict__ e1b, float* __restrict__ pb) {
    __shared__ float ps[HH];
    int b = blockIdx.y;
    for (int idx = threadIdx.x; idx < HH; idx += 256) ps[idx] = ht[(size_t)idx * BB + b];
    __syncthreads();
    int o = blockIdx.x * 256 + threadIdx.x;
    if (o >= EV1) return;
    float acc = e1b[o];
    for (int k = 0; k < HH; k++) acc += ps[k] * e1at[(size_t)k * EV1 + o];
    pb[b * EV1 + o] = acc;
}

// ---------------- fused e3 + e4 tail ----------------
__global__ void k_e34(const float* __restrict__ e2out, const float* __restrict__ e3t,
                      const float* __restrict__ e3b, const float* __restrict__ e4w,
                      const float* __restrict__ e4b, float* __restrict__ out) {
    __shared__ float wt[EV2 * EV3];
    for (int idx = threadIdx.x; idx < EV2 * EV3; idx += 256) wt[idx] = e3t[idx];
    __syncthreads();
    int r = blockIdx.x * 256 + threadIdx.x;
    if (r >= ROWS) return;
    float h3[EV3];
#pragma unroll
    for (int o3 = 0; o3 < EV3; o3++) h3[o3] = e3b[o3];
    for (int k = 0; k < EV2; k++) {
        float v = e2out[(size_t)r * EV2 + k];
#pragma unroll
        for (int o3 = 0; o3 < EV3; o3++) h3[o3] += v * wt[k * EV3 + o3];
    }
    float acc = e4b[0];
#pragma unroll
    for (int o3 = 0; o3 < EV3; o3++) acc += fmaxf(h3[o3], 0.f) * e4w[o3];
    out[r] = fmaxf(acc, 0.f);
}

// ---------------- host launch ----------------
extern "C" void kernel_launch(void* const* d_in, const int* in_sizes, int n_in,
                              void* d_out, int out_size, void* d_ws, size_t ws_size,
                              hipStream_t stream) {
    const float* x    = (const float*)d_in[0];
    const float* w_ih = (const float*)d_in[1];
    const float* w_hh = (const float*)d_in[2];
    const float* b_ih = (const float*)d_in[3];
    const float* b_hh = (const float*)d_in[4];
    const float* q1_w = (const float*)d_in[5];
    const float* q1_b = (const float*)d_in[6];
    const float* q2_w = (const float*)d_in[7];
    const float* q2_b = (const float*)d_in[8];
    const float* e1_w = (const float*)d_in[9];
    const float* e1_b = (const float*)d_in[10];
    const float* e2_w = (const float*)d_in[11];
    const float* e2_b = (const float*)d_in[12];
    const float* e3_w = (const float*)d_in[13];
    const float* e3_b = (const float*)d_in[14];
    const float* e4_w = (const float*)d_in[15];
    const float* e4_b = (const float*)d_in[16];
    float* out = (float*)d_out;
    float* ws = (float*)d_ws;

    // ---- workspace layout (float offsets) ----
    // regionA (23M floats), phase-aliased:
    //  pack/xg : wf [0,4.53M) | xg [4.6M,10.75M) | seq_p [10.8M,11.13M) | wih_p [11.2M,13.13M)
    //  LSTM    : wf [0,4.53M)   (xg dead after xgT)
    //  q1      : pairs_p [0,10.16M) | q1out_p [10.2M,22.9M)   (wf dead)
    //  e1      : e1out_p [0,10.16M)  (pairs_p dead; q1out_p dead after q2)
    //  e2      : e1out_p | e2out [20.4M,21.99M)
    size_t off = 0;
    float* seq    = ws + off; off += (size_t)NN * BB * EE;   // 262,144
    size_t regionA = off; off += 23000000;
    short* wf       = (short*)(ws + regionA);                // 9,048,064 sh
    float* xg       = ws + regionA + 4600000;                // 6,144,000 fl
    short* seq_p    = (short*)(ws + regionA + 10800000);     // 655,360 sh
    short* wih_p    = (short*)(ws + regionA + 11200000);     // 3,850,240 sh
    short* pairs_p  = (short*)(ws + regionA);                // 20,316,160 sh
    short* q1out_p  = (short*)(ws + regionA + 10200000);     // 25,395,200 sh (hi/lo)
    short* e1out_p  = (short*)(ws + regionA);                // 20,316,160 sh (bf16)
    float* e2out    = ws + regionA + 20400000;               // 1,587,200 fl
    float* xgT    = ws + off; off += 7618560;                // 6,144,000 fl; q2out_p alias
    short* q2out_p  = (short*)xgT;                           // 7,618,560 sh (bf16)
    float* ht     = ws + off; off += BH;
    float* ct     = ws + off; off += BH;
    short* hbuf   = (short*)(ws + off); off += 96256;        // 2 x HSZ shorts
    short* q1w_p  = (short*)(ws + off); off += 409600;
    short* q2w_p  = (short*)(ws + off); off += 291840;
    short* e1w_p  = (short*)(ws + off); off += 409600;
    short* e2w_p  = (short*)(ws + off); off += 163840;
    float* e1at   = ws + off; off += (size_t)HH * EV1;
    float* e3t    = ws + off; off += 1024;
    float* pb     = ws + off; off += BB * EV1;
    float* q1beff = ws + off; off += 1024;
    float* bsum   = ws + off; off += 6016;
    int*   iijj   = (int*)(ws + off); off += 1024;

    dim3 tb(32, 8);

    // init
    k_iijj<<<1, 512, 0, stream>>>(iijj);
    k_q1beff<<<3, 256, 0, stream>>>(q1_w, q1_b, q1beff);
    k_addb<<<24, 256, 0, stream>>>(b_ih, b_hh, bsum, G4);
    k_zero<<<188, 256, 0, stream>>>(ct, BH);
    k_zero<<<376, 256, 0, stream>>>((float*)hbuf, 96256);

    // weight transforms
    k_pack_wf<<<dim3(LKT, LBLK), 256, 0, stream>>>(w_hh, wf);
    k_transpose<<<dim3(47, 32), tb, 0, stream>>>(e1_w, e1at, EV1, HH + QO, 0, HH);
    k_transpose<<<dim3(4, 1), tb, 0, stream>>>(e3_w, e3t, EV3, EV2, 0, EV2);
    k_pack<<<dim3(8, 47), 256, 0, stream>>>(w_ih, EE, 0, G4, EE, wih_p);
    k_pack<<<dim3(16, 5), 256, 0, stream>>>(q1_w, QIN, 0, Q1O, QIN, q1w_p);
    k_pack<<<dim3(19, 3), 256, 0, stream>>>(q2_w, Q1O, 0, QO, Q1O, q2w_p);
    k_pack<<<dim3(10, 8), 256, 0, stream>>>(e1_w, HH + QO, HH, EV1, QO, e1w_p);
    k_pack<<<dim3(32, 1), 256, 0, stream>>>(e2_w, EV1, 0, EV2, EV1, e2w_p);

    // sort + pack seq + x-side gates (xg = seq @ w_ih^T + bsum), transpose to [n][j][b]
    k_sort<<<32, 256, 0, stream>>>(x, seq);
    k_pack<<<dim3(8, 8), 256, 0, stream>>>(seq, EE, 0, 1024, EE, seq_p);
    k_gemm_t<2, 2><<<8 * 47 * 1, 256, 0, stream>>>(seq_p, 8, wih_p, bsum, nullptr,
                                                   xg, nullptr, 0, 1024, EE, G4, 0);
    k_xgt<<<dim3(188, 1, 32), tb, 0, stream>>>(xg, xgT);

    // LSTM: 32 fused steps, double-buffered h planes (kernel-boundary coherence)
    for (int nstep = 0; nstep < NN; nstep++) {
        const short* hr = hbuf + (size_t)(nstep & 1) * HSZ;
        short* hw = hbuf + (size_t)((nstep + 1) & 1) * HSZ;
        k_lstm_step<<<LBLK, 512, 0, stream>>>(wf, hr, hw,
                                              xgT + (size_t)nstep * (G4 * BB), ct, ht);
    }

    // evaluator plan-side bias (includes e1_b)
    k_pb<<<dim3(4, BB), 256, 0, stream>>>(ht, e1at, e1_b, pb);

    // pair MLP (packed pipeline; pairs_p overwrites dead wf — after LSTM)
    k_pairs<<<7936, 256, 0, stream>>>(x, iijj, pairs_p);
    k_gemm_t<2, 2><<<8 * 5 * 16, 256, 0, stream>>>(pairs_p, 16, q1w_p, q1beff, nullptr,
                                                   nullptr, q1out_p, 20, ROWS, QIN, Q1O, 1);
    k_gemm_t<2, 1><<<8 * 3 * 16, 256, 0, stream>>>(q1out_p, 20, q2w_p, q2_b, nullptr,
                                                   nullptr, q2out_p, 12, ROWS, Q1O, QO, 1);
    k_gemm_t<1, 1><<<8 * 8 * 16, 256, 0, stream>>>(q2out_p, 12, e1w_p, nullptr, pb,
                                                   nullptr, e1out_p, 32, ROWS, QO, EV1, 1);
    k_gemm_t<1, 1><<<8 * 1 * 16, 256, 0, stream>>>(e1out_p, 32, e2w_p, e2_b, nullptr,
                                                   e2out, nullptr, 0, ROWS, EV1, EV2, 1);
    k_e34<<<62, 256, 0, stream>>>(e2out, e3t, e3_b, e4_w, e4_b, out);
}